// Round 9
// baseline (701.522 us; speedup 1.0000x reference)
//
#include <hip/hip_runtime.h>
#include <cstddef>

// ---------------------------------------------------------------------------
// FastGCN round 9: layer-1 intermediate H stored as bf16 (halves the random
// gather payload in k_agg1, the measured top dispatch: 153us, FETCH 347MB).
// Accumulation stays fp32; layer 2 stays fp32 end-to-end.
// ---------------------------------------------------------------------------

typedef unsigned int uint32;
typedef unsigned short ushort16;

__device__ __forceinline__ uint32 f2bf(float f) {        // fp32 -> bf16 (RNE)
    uint32 u = __float_as_uint(f);
    return (u + 0x7fffu + ((u >> 16) & 1u)) >> 16;
}
__device__ __forceinline__ float bf_lo(uint32 u) {       // low bf16 of packed pair
    return __uint_as_float(u << 16);
}
__device__ __forceinline__ float bf_hi(uint32 u) {       // high bf16 of packed pair
    return __uint_as_float(u & 0xffff0000u);
}

__global__ __launch_bounds__(256) void k_deg(const int* __restrict__ dst,
                                             int* __restrict__ cnt, int E) {
    int e = blockIdx.x * 256 + threadIdx.x;
    if (e < E) atomicAdd(&cnt[dst[e]], 1);
}

__global__ __launch_bounds__(256) void k_dis(const int* __restrict__ cnt,
                                             float* __restrict__ dis, int n) {
    int i = blockIdx.x * 256 + threadIdx.x;
    if (i < n) dis[i] = rsqrtf((float)(cnt[i] + 1));   // +1 = self-loop
}

// exclusive scan, stage 1: per-block scan (block=256), block totals -> bsum
__global__ __launch_bounds__(256) void k_scan_block(const int* __restrict__ cnt,
                                                    int* __restrict__ rowstart,
                                                    int* __restrict__ bsum, int n) {
    __shared__ int sm[256];
    int i = blockIdx.x * 256 + threadIdx.x;
    int v = (i < n) ? cnt[i] : 0;
    sm[threadIdx.x] = v;
    __syncthreads();
    for (int ofs = 1; ofs < 256; ofs <<= 1) {
        int t = (threadIdx.x >= (unsigned)ofs) ? sm[threadIdx.x - ofs] : 0;
        __syncthreads();
        sm[threadIdx.x] += t;
        __syncthreads();
    }
    if (i < n) rowstart[i] = sm[threadIdx.x] - v;        // exclusive within block
    if (threadIdx.x == 255) bsum[blockIdx.x] = sm[255];  // block total
}

// stage 2: single block, exclusive scan of block totals (chunked, carry)
__global__ __launch_bounds__(1024) void k_scan_top(int* __restrict__ bsum, int nb) {
    __shared__ int sm[1024];
    __shared__ int carry;
    if (threadIdx.x == 0) carry = 0;
    __syncthreads();
    for (int base = 0; base < nb; base += 1024) {
        int idx = base + threadIdx.x;
        int v = (idx < nb) ? bsum[idx] : 0;
        sm[threadIdx.x] = v;
        __syncthreads();
        for (int ofs = 1; ofs < 1024; ofs <<= 1) {
            int t = (threadIdx.x >= (unsigned)ofs) ? sm[threadIdx.x - ofs] : 0;
            __syncthreads();
            sm[threadIdx.x] += t;
            __syncthreads();
        }
        if (idx < nb) bsum[idx] = sm[threadIdx.x] - v + carry;  // exclusive + carry
        __syncthreads();
        if (threadIdx.x == 0) carry += sm[1023];
        __syncthreads();
    }
}

// stage 3: add block bases; zero the scatter cursor
__global__ __launch_bounds__(256) void k_scan_add(int* __restrict__ rowstart,
                                                  const int* __restrict__ bsum,
                                                  int* __restrict__ cursor, int n) {
    int i = blockIdx.x * 256 + threadIdx.x;
    if (i < n) {
        rowstart[i] += bsum[blockIdx.x];
        cursor[i] = 0;
    }
}

// scatter edges into CSR slots; cursor[i] ends equal to deg[i] (no self-loop)
__global__ __launch_bounds__(256) void k_scatter(const int* __restrict__ src,
                                                 const int* __restrict__ dst,
                                                 const float* __restrict__ dis,
                                                 const int* __restrict__ rowstart,
                                                 int* __restrict__ cursor,
                                                 int* __restrict__ esrc,
                                                 float* __restrict__ enorm, int E) {
    int e = blockIdx.x * 256 + threadIdx.x;
    if (e >= E) return;
    int s = src[e], d = dst[e];
    int pos = rowstart[d] + atomicAdd(&cursor[d], 1);
    esrc[pos] = s;
    enorm[pos] = dis[s] * dis[d];
}

// ---------------------------------------------------------------------------
// LDS-tiled GEMM, fp32 out: out[n,M] = X[n,128] @ W[128,M].
// Block = 256 threads (4 waves), tile = 64 rows; x-tile in LDS (coalesced);
// wave w owns cols [w*M/4, +M/4); W reads wave-uniform -> scalar, L2-resident.
// ---------------------------------------------------------------------------
template <int M>
__global__ __launch_bounds__(256) void k_gemm_t(const float* __restrict__ X,
                                                const float* __restrict__ W,
                                                float* __restrict__ out, int n) {
    constexpr int CPW = M / 4;
    __shared__ float4 xs4[64 * 33];
    const int tid = threadIdx.x;
    const int rowbase = blockIdx.x * 64;

    const float4* Xv = (const float4*)X;
#pragma unroll
    for (int i = 0; i < 8; ++i) {
        int idx = i * 256 + tid;
        int row = idx >> 5, c4 = idx & 31;
        int gr = rowbase + row;
        float4 v = make_float4(0.f, 0.f, 0.f, 0.f);
        if (gr < n) v = Xv[(size_t)gr * 32 + c4];
        xs4[row * 33 + c4] = v;
    }
    __syncthreads();

    const int lane = tid & 63;
    int colbase = (tid >> 6) * CPW;
    colbase = __builtin_amdgcn_readfirstlane(colbase);

    float acc[CPW];
#pragma unroll
    for (int j = 0; j < CPW; ++j) acc[j] = 0.f;

    for (int k4 = 0; k4 < 32; ++k4) {
        float4 xv = xs4[lane * 33 + k4];
        const float* w0 = W + (size_t)(k4 * 4) * M + colbase;
#pragma unroll
        for (int j = 0; j < CPW; ++j) acc[j] = fmaf(xv.x, w0[j], acc[j]);
#pragma unroll
        for (int j = 0; j < CPW; ++j) acc[j] = fmaf(xv.y, w0[M + j], acc[j]);
#pragma unroll
        for (int j = 0; j < CPW; ++j) acc[j] = fmaf(xv.z, w0[2 * M + j], acc[j]);
#pragma unroll
        for (int j = 0; j < CPW; ++j) acc[j] = fmaf(xv.w, w0[3 * M + j], acc[j]);
    }

    int gr = rowbase + lane;
    if (gr < n) {
        float* o = out + (size_t)gr * M + colbase;
#pragma unroll
        for (int j = 0; j < CPW; ++j) o[j] = acc[j];
    }
}

// Same GEMM but M=128 fixed and bf16 output (packed pairs), for H1.
__global__ __launch_bounds__(256) void k_gemm_bf16(const float* __restrict__ X,
                                                   const float* __restrict__ W,
                                                   uint32* __restrict__ outb,  // n x 64 packed
                                                   int n) {
    constexpr int M = 128, CPW = 32;
    __shared__ float4 xs4[64 * 33];
    const int tid = threadIdx.x;
    const int rowbase = blockIdx.x * 64;

    const float4* Xv = (const float4*)X;
#pragma unroll
    for (int i = 0; i < 8; ++i) {
        int idx = i * 256 + tid;
        int row = idx >> 5, c4 = idx & 31;
        int gr = rowbase + row;
        float4 v = make_float4(0.f, 0.f, 0.f, 0.f);
        if (gr < n) v = Xv[(size_t)gr * 32 + c4];
        xs4[row * 33 + c4] = v;
    }
    __syncthreads();

    const int lane = tid & 63;
    int colbase = (tid >> 6) * CPW;
    colbase = __builtin_amdgcn_readfirstlane(colbase);

    float acc[CPW];
#pragma unroll
    for (int j = 0; j < CPW; ++j) acc[j] = 0.f;

    for (int k4 = 0; k4 < 32; ++k4) {
        float4 xv = xs4[lane * 33 + k4];
        const float* w0 = W + (size_t)(k4 * 4) * M + colbase;
#pragma unroll
        for (int j = 0; j < CPW; ++j) acc[j] = fmaf(xv.x, w0[j], acc[j]);
#pragma unroll
        for (int j = 0; j < CPW; ++j) acc[j] = fmaf(xv.y, w0[M + j], acc[j]);
#pragma unroll
        for (int j = 0; j < CPW; ++j) acc[j] = fmaf(xv.z, w0[2 * M + j], acc[j]);
#pragma unroll
        for (int j = 0; j < CPW; ++j) acc[j] = fmaf(xv.w, w0[3 * M + j], acc[j]);
    }

    int gr = rowbase + lane;
    if (gr < n) {
        uint32* o = outb + (size_t)gr * 64 + (colbase >> 1);
#pragma unroll
        for (int j = 0; j < CPW; j += 2)
            o[j >> 1] = f2bf(acc[j]) | (f2bf(acc[j + 1]) << 16);
    }
}

// agg layer 1 (bf16 H): one wave per dst node, one packed bf16 pair per lane.
// X2 = relu( dis^2*H[i] + sum_e norm*H[src] + b1 )   (fp32 accumulate/out)
__global__ __launch_bounds__(256) void k_agg1(const uint32* __restrict__ Hb,
                                              const float* __restrict__ dis,
                                              const int* __restrict__ esrc,
                                              const float* __restrict__ enorm,
                                              const int* __restrict__ rowstart,
                                              const int* __restrict__ ecnt,
                                              const float* __restrict__ b1,
                                              float* __restrict__ X2, int n) {
    int wid = (blockIdx.x * 256 + threadIdx.x) >> 6;
    int lane = threadIdx.x & 63;
    if (wid >= n) return;
    int beg = rowstart[wid];
    int end = beg + ecnt[wid];
    float di = dis[wid];
    uint32 hs = Hb[(size_t)wid * 64 + lane];
    float d2 = di * di;
    float ax = bf_lo(hs) * d2;
    float ay = bf_hi(hs) * d2;
    for (int e = beg; e < end; ++e) {
        int s = esrc[e];
        float nm = enorm[e];
        uint32 hv = Hb[(size_t)s * 64 + lane];
        ax = fmaf(nm, bf_lo(hv), ax);
        ay = fmaf(nm, bf_hi(hv), ay);
    }
    float2 b = ((const float2*)b1)[lane];
    float2 r;
    r.x = fmaxf(ax + b.x, 0.f);
    r.y = fmaxf(ay + b.y, 0.f);
    ((float2*)X2)[(size_t)wid * 64 + lane] = r;
}

// agg layer 2 (fp32): one wave per dst node, lanes 0..39 one col each.
// out = dis^2*H2[i] + sum_e norm*H2[src] + b2
__global__ __launch_bounds__(256) void k_agg2(const float* __restrict__ H2,
                                              const float* __restrict__ dis,
                                              const int* __restrict__ esrc,
                                              const float* __restrict__ enorm,
                                              const int* __restrict__ rowstart,
                                              const int* __restrict__ ecnt,
                                              const float* __restrict__ b2,
                                              float* __restrict__ out, int n) {
    int wid = (blockIdx.x * 256 + threadIdx.x) >> 6;
    int lane = threadIdx.x & 63;
    if (wid >= n) return;
    int beg = rowstart[wid];
    int end = beg + ecnt[wid];
    float di = dis[wid];
    bool ok = lane < 40;
    float acc = 0.f;
    if (ok) acc = fmaf(H2[(size_t)wid * 40 + lane], di * di, b2[lane]);
    for (int e = beg; e < end; ++e) {
        int s = esrc[e];
        float nm = enorm[e];
        if (ok) acc = fmaf(nm, H2[(size_t)s * 40 + lane], acc);
    }
    if (ok) out[(size_t)wid * 40 + lane] = acc;
}

static inline int cdiv(long long a, long long b) { return (int)((a + b - 1) / b); }

extern "C" void kernel_launch(void* const* d_in, const int* in_sizes, int n_in,
                              void* d_out, int out_size, void* d_ws, size_t ws_size,
                              hipStream_t stream) {
    const float* x  = (const float*)d_in[0];
    const float* W1 = (const float*)d_in[1];
    const float* b1 = (const float*)d_in[2];
    const float* W2 = (const float*)d_in[3];
    const float* b2 = (const float*)d_in[4];
    const int*   ei = (const int*)d_in[5];

    const int n = in_sizes[0] / 128;   // 170000
    const int E = in_sizes[5] / 2;     // 1200000
    const int* srcv = ei;
    const int* dstv = ei + E;
    float* out = (float*)d_out;

    const int nb = cdiv(n, 256);       // scan blocks

    // workspace carve-up (256B-aligned)
    char* w = (char*)d_ws;
    size_t off = 0;
    auto carve = [&](size_t bytes) {
        void* p = w + off;
        off += (bytes + 255) & ~(size_t)255;
        return p;
    };
    int*    cnt      = (int*)carve((size_t)n * 4);     // deg, then scatter cursor
    float*  dis      = (float*)carve((size_t)n * 4);
    int*    rowstart = (int*)carve((size_t)n * 4);
    int*    bsum     = (int*)carve((size_t)nb * 4);
    int*    esrc     = (int*)carve((size_t)E * 4);
    float*  enorm    = (float*)carve((size_t)E * 4);
    uint32* Hb       = (uint32*)carve((size_t)n * 64 * 4);  // H1 bf16 packed (n x 128)
    float*  Xbuf     = (float*)carve((size_t)n * 128 * 4);  // X2 fp32
    float*  H2buf    = (float*)carve((size_t)n * 40 * 4);   // H2 fp32
    (void)ws_size;

    // degree + norms + CSR build
    hipMemsetAsync(cnt, 0, (size_t)n * 4, stream);
    k_deg<<<cdiv(E, 256), 256, 0, stream>>>(dstv, cnt, E);
    k_dis<<<cdiv(n, 256), 256, 0, stream>>>(cnt, dis, n);
    k_scan_block<<<nb, 256, 0, stream>>>(cnt, rowstart, bsum, n);
    k_scan_top<<<1, 1024, 0, stream>>>(bsum, nb);
    k_scan_add<<<nb, 256, 0, stream>>>(rowstart, bsum, cnt, n);  // cnt -> cursor
    k_scatter<<<cdiv(E, 256), 256, 0, stream>>>(srcv, dstv, dis, rowstart, cnt,
                                                esrc, enorm, E);
    // after scatter, cnt[i] == in-degree of i (CSR segment length)

    // layer 1: H1 = x@W1 (bf16) ; X2 = relu(agg(H1) + b1) (fp32)
    k_gemm_bf16<<<cdiv(n, 64), 256, 0, stream>>>(x, W1, Hb, n);
    k_agg1<<<cdiv(n, 4), 256, 0, stream>>>(Hb, dis, esrc, enorm, rowstart, cnt,
                                           b1, Xbuf, n);

    // layer 2: H2 = X2@W2 ; out = agg(H2) + b2   (fp32)
    k_gemm_t<40><<<cdiv(n, 64), 256, 0, stream>>>(Xbuf, W2, H2buf, n);
    k_agg2<<<cdiv(n, 4), 256, 0, stream>>>(H2buf, dis, esrc, enorm, rowstart, cnt,
                                           b2, out, n);
}